// Round 20
// baseline (254.219 us; speedup 1.0000x reference)
//
#include <hip/hip_runtime.h>
#include <math.h>

#define NN   10000          // nodes
#define NE   160000         // raw edges
#define NET  (NE + NN)      // edges + self loops = 170000
#define FIN  70
#define HIDC 256
#define NH   4
#define D1   1024           // NH*HIDC
#define SLOPE 0.2f
#define KL1  96             // K for layer-1 GEMM (70 padded to 96)
#define NPB  32             // pooling buckets
#define BCAP 64             // per-dst edge bucket capacity (deg mean 17, P(>63)~1e-15)

typedef float f32x4 __attribute__((ext_vector_type(4)));
typedef short bf16x8 __attribute__((ext_vector_type(8)));
typedef unsigned short u16x4 __attribute__((ext_vector_type(4)));

__device__ __forceinline__ unsigned short f32_to_bf16(float f) {
    unsigned int u = __float_as_uint(f);
    unsigned int r = u + 0x7fffu + ((u >> 16) & 1u);   // round-to-nearest-even
    return (unsigned short)(r >> 16);
}
__device__ __forceinline__ float bf16_to_f32(unsigned short h) {
    return __uint_as_float(((unsigned int)h) << 16);
}
__device__ __forceinline__ float leaky(float e) { return (e > 0.f) ? e : SLOPE * e; }

// async 16B global->LDS DMA; LDS dest = wave base + lane*16 (linear), global src per-lane
__device__ __forceinline__ void cp16(const unsigned short* g, unsigned short* l) {
    __builtin_amdgcn_global_load_lds((const __attribute__((address_space(1))) unsigned int*)g,
                                     (__attribute__((address_space(3))) unsigned int*)l,
                                     16, 0, 0);
}

// ---------------- fused prep: W2t | W1t | xb | bucket scatter | att_x (self-computed was/wad) ----
// blocks: [0,64) W2t tiles ; [64,80) W1t tiles ; [80,120) xb ; [120,785) scatter ; [785,942) att_x
__global__ __launch_bounds__(256) void k_prep(const float* __restrict__ W2,
                                              unsigned short* __restrict__ W2t,
                                              const float* __restrict__ W1,
                                              unsigned short* __restrict__ W1t,
                                              const float* __restrict__ asrc,
                                              const float* __restrict__ adst,
                                              const float* __restrict__ x,
                                              unsigned short* __restrict__ xb,
                                              const int* __restrict__ ei,
                                              int* __restrict__ cnt,
                                              int* __restrict__ ssrc,
                                              float* __restrict__ asn,
                                              float* __restrict__ adn) {
    __shared__ __align__(16) char smem[20480];   // max branch: att_x 64*71*4 + 2*4*70*4 = 20416
    int b = blockIdx.x, t = threadIdx.x;
    int lane = t & 63, wave = t >> 6;
    if (b < 64) {
        // W2 [1024][256] f32 -> W2t [256][1024] bf16, LDS-tiled 64x64 transpose
        unsigned short (*tl)[68] = (unsigned short (*)[68])smem;
        int kk0 = (b >> 2) * 64, n0 = (b & 3) * 64;
        for (int i = t; i < 64 * 64; i += 256) {
            int nl = i & 63, kl = i >> 6;          // coalesced read
            tl[nl][kl] = f32_to_bf16(W2[(size_t)(kk0 + kl) * HIDC + n0 + nl]);
        }
        __syncthreads();
        for (int i = t; i < 64 * 64; i += 256) {
            int kl = i & 63, nl = i >> 6;          // coalesced write
            W2t[(size_t)(n0 + nl) * 1024 + kk0 + kl] = tl[nl][kl];
        }
    } else if (b < 80) {
        // W1 [70][1024] f32 -> W1t [1024][96] bf16 (zero-pad K), LDS-tiled 64x96
        unsigned short (*tl)[97] = (unsigned short (*)[97])smem;
        int r0 = (b - 64) * 64;
        for (int i = t; i < 64 * 96; i += 256) {
            int rl = i & 63, kk = i >> 6;
            float w = (kk < FIN) ? W1[(size_t)kk * D1 + r0 + rl] : 0.f;
            tl[rl][kk] = f32_to_bf16(w);
        }
        __syncthreads();
        for (int i = t; i < 64 * 96; i += 256) {
            int kk = i % 96, rl = i / 96;
            W1t[(size_t)(r0 + rl) * KL1 + kk] = tl[rl][kk];
        }
    } else if (b < 120) {
        // x -> bf16, vectorized float4 / u16x4 (17500 elems = 4375 vec4 per job)
        size_t base = (size_t)(b - 80) * 17500;
        for (int v = t; v < 4375; v += 256) {
            float4 xv = *(const float4*)&x[base + v * 4];
            u16x4 o;
            o[0] = f32_to_bf16(xv.x); o[1] = f32_to_bf16(xv.y);
            o[2] = f32_to_bf16(xv.z); o[3] = f32_to_bf16(xv.w);
            *(u16x4*)&xb[base + v * 4] = o;
        }
    } else if (b < 785) {
        int e = (b - 120) * 256 + t;
        if (e < NET) {
            int src, dst;
            if (e < NE) { src = ei[e]; dst = ei[NE + e]; }
            else        { src = e - NE; dst = src; }
            int pos = atomicAdd(&cnt[dst], 1);
            if (pos < BCAP) ssrc[dst * BCAP + pos] = src;
        }
    } else {
        // att_x with block-local was/wad (deterministic; reads L2-resident W1)
        int n0 = (b - 785) * 64;
        float (*xs)[71] = (float (*)[71])smem;                 // 18.2 KB
        float* lws = (float*)(smem + 64 * 71 * 4);             // [4][70]
        float* lwd = lws + NH * FIN;                           // [4][70]
        for (int i = t; i < 64 * FIN; i += 256) {
            int r = i / FIN, k = i % FIN;
            int n = n0 + r;
            xs[r][k] = (n < NN) ? x[(size_t)n * FIN + k] : 0.f;
        }
        // lane owns cols [lane*16, lane*16+16) — one head per 16-lane group
        float ar[16], dr[16];
#pragma unroll
        for (int q = 0; q < 4; q++) {
            float4 av = *(const float4*)&asrc[lane * 16 + q * 4];
            float4 dv = *(const float4*)&adst[lane * 16 + q * 4];
            ar[q*4+0]=av.x; ar[q*4+1]=av.y; ar[q*4+2]=av.z; ar[q*4+3]=av.w;
            dr[q*4+0]=dv.x; dr[q*4+1]=dv.y; dr[q*4+2]=dv.z; dr[q*4+3]=dv.w;
        }
        for (int k = wave; k < FIN; k += 4) {
            const float* row = W1 + (size_t)k * D1 + lane * 16;
            float s = 0.f, dd = 0.f;
#pragma unroll
            for (int q = 0; q < 4; q++) {
                float4 wv = *(const float4*)(row + q * 4);
                s  += wv.x*ar[q*4] + wv.y*ar[q*4+1] + wv.z*ar[q*4+2] + wv.w*ar[q*4+3];
                dd += wv.x*dr[q*4] + wv.y*dr[q*4+1] + wv.z*dr[q*4+2] + wv.w*dr[q*4+3];
            }
#pragma unroll
            for (int off = 1; off < 16; off <<= 1) { s += __shfl_xor(s, off); dd += __shfl_xor(dd, off); }
            if ((lane & 15) == 0) { int h = lane >> 4; lws[h * FIN + k] = s; lwd[h * FIN + k] = dd; }
        }
        __syncthreads();
        if (t < 64) {
            int n = n0 + t;
            if (n < NN) {
                float a[NH] = {}, d2[NH] = {};
                for (int k = 0; k < FIN; k++) {
                    float xv = xs[t][k];
#pragma unroll
                    for (int h = 0; h < NH; h++) {
                        a[h]  += xv * lws[h * FIN + k];
                        d2[h] += xv * lwd[h * FIN + k];
                    }
                }
#pragma unroll
                for (int h = 0; h < NH; h++) { asn[n*NH+h] = a[h]; adn[n*NH+h] = d2[h]; }
            }
        }
    }
}

// ---------------- fused softmax(H=4) + layer-1 aggregation (wave-per-dst, 4 dst/block) ---------
__global__ __launch_bounds__(256) void k_sm_aggX(const int* __restrict__ cnt,
                                                 const int* __restrict__ ssrc,
                                                 const float* __restrict__ as,
                                                 const float* __restrict__ ad,
                                                 const unsigned short* __restrict__ xb,
                                                 unsigned short* __restrict__ aggXhi) {
    int t = threadIdx.x, lane = t & 63, wave = t >> 6;
    int d = blockIdx.x * 4 + wave;
    int n = cnt[d]; if (n > BCAP) n = BCAP;
    float4 adv = *(const float4*)&ad[d * NH];
    bool v0 = lane < n;
    int s0 = 0;
    float e0[NH];
    if (v0) {
        s0 = ssrc[d * BCAP + lane];
        float4 a4 = *(const float4*)&as[s0 * NH];
        e0[0] = leaky(a4.x + adv.x); e0[1] = leaky(a4.y + adv.y);
        e0[2] = leaky(a4.z + adv.z); e0[3] = leaky(a4.w + adv.w);
    } else { e0[0] = e0[1] = e0[2] = e0[3] = -1e30f; }
    float m[NH] = {e0[0], e0[1], e0[2], e0[3]};
#pragma unroll
    for (int h = 0; h < NH; h++)
        for (int off = 32; off > 0; off >>= 1)
            m[h] = fmaxf(m[h], __shfl_xor(m[h], off));
    float sum[NH];
#pragma unroll
    for (int h = 0; h < NH; h++) sum[h] = v0 ? expf(e0[h] - m[h]) : 0.f;
#pragma unroll
    for (int h = 0; h < NH; h++)
        for (int off = 32; off > 0; off >>= 1)
            sum[h] += __shfl_xor(sum[h], off);
    __shared__ float al4[4][64][4];
    __shared__ int   sid[4][64];
    if (v0) {
        sid[wave][lane] = s0;
#pragma unroll
        for (int h = 0; h < NH; h++) al4[wave][lane][h] = expf(e0[h] - m[h]) / (sum[h] + 1e-16f);
    }
    __syncthreads();
    float ac[NH][2] = {};
#pragma unroll 4
    for (int j = 0; j < n; j++) {
        int s = sid[wave][j];
        float4 al = *(const float4*)al4[wave][j];
        float xv0 = bf16_to_f32(xb[(size_t)s * FIN + lane]);
        float xv1 = (lane < FIN - 64) ? bf16_to_f32(xb[(size_t)s * FIN + 64 + lane]) : 0.f;
        ac[0][0] += al.x * xv0; ac[0][1] += al.x * xv1;
        ac[1][0] += al.y * xv0; ac[1][1] += al.y * xv1;
        ac[2][0] += al.z * xv0; ac[2][1] += al.z * xv1;
        ac[3][0] += al.w * xv0; ac[3][1] += al.w * xv1;
    }
#pragma unroll
    for (int h = 0; h < NH; h++) {
        size_t base = ((size_t)d * NH + h) * KL1;
        aggXhi[base + lane] = f32_to_bf16(ac[h][0]);
        if (lane < 32) {  // k in [64,96): data for lane<6, zero pad for 6<=lane<32
            float v1 = (lane < FIN - 64) ? ac[h][1] : 0.f;
            aggXhi[base + 64 + lane] = f32_to_bf16(v1);
        }
    }
}

// ---------------- MFMA GEMM layer 1: single-stage K=96 (one barrier per block) ----------
__global__ __launch_bounds__(256) void k_gemm_l1(const unsigned short* __restrict__ aggXhi,
                                                 const unsigned short* __restrict__ W1t,
                                                 const float* __restrict__ b1,
                                                 unsigned short* __restrict__ x2hi) {
    __shared__ unsigned short As[128 * 96];   // 24 KB
    __shared__ unsigned short Bs[128 * 96];   // 24 KB
    int t = threadIdx.x;
    int n0 = blockIdx.x * 128;
    int cb = blockIdx.y * 128;       // col within head's 256
    int h  = blockIdx.z;
    int lane = t & 63, wave = t >> 6, quad = lane >> 4, l16 = lane & 15;
    int wr = (wave & 1) * 64, wc = (wave >> 1) * 64;
#pragma unroll
    for (int q = 0; q < 6; q++) {
        int g = q * 256 + t;
        int row = g / 12, gr = g % 12;
        int ra = n0 + row; if (ra >= NN) ra = NN - 1;
        cp16(aggXhi + ((size_t)ra * NH + h) * KL1 + gr * 8, As + g * 8);
        cp16(W1t + (size_t)(h * 256 + cb + row) * KL1 + gr * 8, Bs + g * 8);
    }
    __syncthreads();
    f32x4 acc[4][4] = {};
#pragma unroll
    for (int kc = 0; kc < 3; kc++) {
        bf16x8 af[4], bf[4];
#pragma unroll
        for (int i = 0; i < 4; i++) af[i] = *(const bf16x8*)&As[(wr + i * 16 + l16) * KL1 + kc * 32 + quad * 8];
#pragma unroll
        for (int j = 0; j < 4; j++) bf[j] = *(const bf16x8*)&Bs[(wc + j * 16 + l16) * KL1 + kc * 32 + quad * 8];
#pragma unroll
        for (int i = 0; i < 4; i++)
#pragma unroll
            for (int j = 0; j < 4; j++)
                acc[i][j] = __builtin_amdgcn_mfma_f32_16x16x32_bf16(af[i], bf[j], acc[i][j], 0, 0, 0);
    }
#pragma unroll
    for (int i = 0; i < 4; i++)
#pragma unroll
        for (int j = 0; j < 4; j++) {
            int colg = h * 256 + cb + wc + j * 16 + l16;
            float bb = b1[colg];
#pragma unroll
            for (int reg = 0; reg < 4; reg++) {
                int r = n0 + wr + i * 16 + quad * 4 + reg;
                if (r >= NN) continue;
                float v = fmaxf(acc[i][j][reg] + bb, 0.f);
                x2hi[(size_t)r * D1 + colg] = f32_to_bf16(v);
            }
        }
}

// ---------------- MFMA GEMM layer 2: BM=64, BN=64, 256 thr (4 waves, 2x2 of 32x32), BK=64 ------
__global__ __launch_bounds__(256) void k_gemm2(const unsigned short* __restrict__ x2hi,
                                               const unsigned short* __restrict__ W2t,
                                               const float* __restrict__ asrc,
                                               const float* __restrict__ adst,
                                               unsigned short* __restrict__ h2bf,
                                               float* __restrict__ as2,
                                               float* __restrict__ ad2) {
    __shared__ unsigned short As[64 * 64];    // 8 KB
    __shared__ unsigned short Bs[64 * 64];    // 8 KB
    int t = threadIdx.x;
    int n0 = blockIdx.x * 64;
    int cb = blockIdx.y * 64;
    int lane = t & 63, wave = t >> 6, quad = lane >> 4, l16 = lane & 15;
    int wr = (wave & 1) * 32, wc = (wave >> 1) * 32;
    const unsigned short* ga[2];
    unsigned short* la[2];
#pragma unroll
    for (int q = 0; q < 2; q++) {
        int g = q * 256 + t;
        int row = g >> 3, gr = g & 7;
        int ra = n0 + row; if (ra >= NN) ra = NN - 1;
        ga[q] = x2hi + (size_t)ra * D1 + gr * 8;
        la[q] = As + g * 8;
    }
    const unsigned short* gb[2];
    unsigned short* lb[2];
#pragma unroll
    for (int q = 0; q < 2; q++) {
        int g = q * 256 + t;
        int col = g >> 3, gr = g & 7;
        gb[q] = W2t + (size_t)(cb + col) * 1024 + gr * 8;
        lb[q] = Bs + g * 8;
    }
    f32x4 acc[2][2] = {};
    for (int kc = 0; kc < 16; kc++) {
        cp16(ga[0] + kc * 64, la[0]);
        cp16(ga[1] + kc * 64, la[1]);
        cp16(gb[0] + kc * 64, lb[0]);
        cp16(gb[1] + kc * 64, lb[1]);
        __syncthreads();
#pragma unroll
        for (int ks = 0; ks < 2; ks++) {
            bf16x8 af[2], bf[2];
#pragma unroll
            for (int i = 0; i < 2; i++) af[i] = *(const bf16x8*)&As[(wr + i * 16 + l16) * 64 + ks * 32 + quad * 8];
#pragma unroll
            for (int j = 0; j < 2; j++) bf[j] = *(const bf16x8*)&Bs[(wc + j * 16 + l16) * 64 + ks * 32 + quad * 8];
#pragma unroll
            for (int i = 0; i < 2; i++)
#pragma unroll
                for (int j = 0; j < 2; j++)
                    acc[i][j] = __builtin_amdgcn_mfma_f32_16x16x32_bf16(af[i], bf[j], acc[i][j], 0, 0, 0);
        }
        __syncthreads();
    }
    float a2[2], d2[2];
#pragma unroll
    for (int j = 0; j < 2; j++) {
        int c = cb + wc + j * 16 + l16;
        a2[j] = asrc[c];
        d2[j] = adst[c];
    }
    float asp[2][4] = {}, adp[2][4] = {};
#pragma unroll
    for (int i = 0; i < 2; i++)
#pragma unroll
        for (int j = 0; j < 2; j++) {
            int c = cb + wc + j * 16 + l16;
#pragma unroll
            for (int reg = 0; reg < 4; reg++) {
                int r = n0 + wr + i * 16 + quad * 4 + reg;
                float v = acc[i][j][reg];
                if (r < NN) h2bf[(size_t)r * HIDC + c] = f32_to_bf16(v);
                asp[i][reg] += v * a2[j];
                adp[i][reg] += v * d2[j];
            }
        }
#pragma unroll
    for (int mask = 1; mask < 16; mask <<= 1)
#pragma unroll
        for (int i = 0; i < 2; i++)
#pragma unroll
            for (int reg = 0; reg < 4; reg++) {
                asp[i][reg] += __shfl_xor(asp[i][reg], mask);
                adp[i][reg] += __shfl_xor(adp[i][reg], mask);
            }
    if (l16 == 0) {
#pragma unroll
        for (int i = 0; i < 2; i++)
#pragma unroll
            for (int reg = 0; reg < 4; reg++) {
                int r = n0 + wr + i * 16 + quad * 4 + reg;
                if (r < NN) {
                    atomicAdd(&as2[r], asp[i][reg]);
                    atomicAdd(&ad2[r], adp[i][reg]);
                }
            }
    }
}

// ---------------- fused softmax(H=1) + layer-2 aggregation + bucketed pool ------------
// wave-per-dst: 4 dsts/block; no fence, no finale (round-8 PMC: per-block __threadfence()
// = L2 writeback on gfx950, 194 us of stall).
__global__ __launch_bounds__(256) void k_sm_aggr2(const int* __restrict__ cnt,
                                                  const int* __restrict__ ssrc,
                                                  const float* __restrict__ as,
                                                  const float* __restrict__ ad,
                                                  const unsigned short* __restrict__ h2bf,
                                                  const float* __restrict__ b,
                                                  float* __restrict__ pooled32) {
    int t = threadIdx.x, lane = t & 63, wave = t >> 6;
    int d = blockIdx.x * 4 + wave;
    int n = cnt[d]; if (n > BCAP) n = BCAP;
    float adv = ad[d];
    bool v0 = lane < n;
    int s0 = v0 ? ssrc[d * BCAP + lane] : 0;
    float e0 = v0 ? leaky(as[s0] + adv) : -1e30f;
    float m = e0;
    for (int off = 32; off > 0; off >>= 1) m = fmaxf(m, __shfl_xor(m, off));
    float ex = v0 ? expf(e0 - m) : 0.f;
    float sum = ex;
    for (int off = 32; off > 0; off >>= 1) sum += __shfl_xor(sum, off);
    float al0 = ex * (1.0f / (sum + 1e-16f));
    float a0 = 0.f, a1 = 0.f, a2v = 0.f, a3 = 0.f;
#pragma unroll 4
    for (int j = 0; j < n; j++) {
        float alj = __shfl(al0, j);          // wave-uniform j -> v_readlane broadcast
        int   sj  = __shfl(s0, j);
        u16x4 hv = *(const u16x4*)&h2bf[(size_t)sj * HIDC + lane * 4];
        a0  += alj * bf16_to_f32(hv[0]);
        a1  += alj * bf16_to_f32(hv[1]);
        a2v += alj * bf16_to_f32(hv[2]);
        a3  += alj * bf16_to_f32(hv[3]);
    }
    float4 bb = *(const float4*)&b[lane * 4];
    __shared__ float sacc[4 * 256];
    *(float4*)&sacc[wave * 256 + lane * 4] = make_float4(fmaxf(a0 + bb.x, 0.f),
                                                         fmaxf(a1 + bb.y, 0.f),
                                                         fmaxf(a2v + bb.z, 0.f),
                                                         fmaxf(a3 + bb.w, 0.f));
    __syncthreads();
    float s = sacc[t] + sacc[256 + t] + sacc[512 + t] + sacc[768 + t];
    atomicAdd(&pooled32[(blockIdx.x & (NPB - 1)) * HIDC + t], s);
}

// ---------------- MLP head: bucket-reduce + 256 -> 128 (gelu exact) -> 1 ----------------
__global__ __launch_bounds__(128) void k_mlp(const float* __restrict__ pooled32,
                                             const float* __restrict__ Wv1,
                                             const float* __restrict__ bv1,
                                             const float* __restrict__ Wv2,
                                             const float* __restrict__ bv2,
                                             float* __restrict__ out) {
    int j = threadIdx.x;
    __shared__ float ps[256];
    for (int c = j; c < HIDC; c += 128) {
        float s = 0.f;
        for (int bkt = 0; bkt < NPB; bkt++) s += pooled32[bkt * HIDC + c];
        ps[c] = s;
    }
    __syncthreads();
    float s = bv1[j];
    const float invn = 1.0f / (float)NN;
    for (int c = 0; c < HIDC; c++)
        s += (ps[c] * invn) * Wv1[c * 128 + j];
    float g = 0.5f * s * (1.0f + erff(s * 0.70710678118654752f));
    float v = g * Wv2[j];
    __shared__ float red[128];
    red[j] = v;
    __syncthreads();
    for (int off = 64; off > 0; off >>= 1) {
        if (j < off) red[j] += red[j + off];
        __syncthreads();
    }
    if (j == 0) out[0] = red[0] + bv2[0];
}

extern "C" void kernel_launch(void* const* d_in, const int* in_sizes, int n_in,
                              void* d_out, int out_size, void* d_ws, size_t ws_size,
                              hipStream_t stream) {
    const float* x_in  = (const float*)d_in[0];
    const int*   ei    = (const int*)d_in[1];
    // d_in[2] = edge_attr: ignored (GATConv has no edge_dim)
    const float* W1    = (const float*)d_in[3];
    const float* asrc1 = (const float*)d_in[4];
    const float* adst1 = (const float*)d_in[5];
    const float* b1    = (const float*)d_in[6];
    const float* W2    = (const float*)d_in[7];
    const float* asrc2 = (const float*)d_in[8];
    const float* adst2 = (const float*)d_in[9];
    const float* b2    = (const float*)d_in[10];
    const float* Wv1   = (const float*)d_in[11];
    const float* bv1   = (const float*)d_in[12];
    const float* Wv2   = (const float*)d_in[13];
    const float* bv2   = (const float*)d_in[14];
    float* out = (float*)d_out;

    char* w = (char*)d_ws;
    auto alloc = [&](size_t bytes) { char* p = w; w += (bytes + 255) & ~(size_t)255; return p; };
    unsigned short* x2hi   = (unsigned short*)alloc(2ull * NN * D1);           // 20.5 MB
    unsigned short* aggXhi = (unsigned short*)alloc(2ull * NN * NH * KL1);     // 7.68 MB
    unsigned short* h2bf = (unsigned short*)alloc(2ull * NN * HIDC);           // 5.12 MB
    unsigned short* xb   = (unsigned short*)alloc(2ull * NN * FIN);            // 1.4 MB
    unsigned short* W2t  = (unsigned short*)alloc(2ull * 256 * 1024);          // 0.52 MB
    unsigned short* W1t  = (unsigned short*)alloc(2ull * NH * 256 * KL1);      // 0.20 MB
    float* as1    = (float*)alloc(sizeof(float) * NN * NH);
    float* ad1    = (float*)alloc(sizeof(float) * NN * NH);
    int*   ssrc   = (int*)alloc(sizeof(int) * NN * BCAP);                      // 2.56 MB
    // single zero-init region: cnt | pooled32 | as2 | ad2 (one memset)
    size_t zbytes = (size_t)NN * 4 + NPB * HIDC * 4 + NN * 4 + NN * 4;
    char*  zbase  = alloc(zbytes);
    int*   cnt      = (int*)zbase;
    float* pooled32 = (float*)(zbase + NN * 4);
    float* as2      = (float*)(zbase + NN * 4 + NPB * HIDC * 4);
    float* ad2      = (float*)(zbase + NN * 4 + NPB * HIDC * 4 + NN * 4);

    hipMemsetAsync(zbase, 0, zbytes, stream);

    // prep: weight conversions + xb + bucket scatter + att_x (self-computed was/wad)
    k_prep<<<64 + 16 + 40 + 665 + 157, 256, 0, stream>>>(
        W2, W2t, W1, W1t, asrc1, adst1, x_in, xb, ei, cnt, ssrc, as1, ad1);

    // ---- layer 1 ----
    // ATTRIBUTION EXPERIMENT (this round only): k_sm_aggX and k_gemm_l1 are idempotent
    // (deterministic overwrites, no atomics). Launch each 3x; dur delta vs the 195.3 us
    // round-13 baseline = 2*(t_aggX + t_gemm_l1). Outputs bit-identical.
    for (int rep = 0; rep < 3; rep++)
        k_sm_aggX<<<NN / 4, 256, 0, stream>>>(cnt, ssrc, as1, ad1, xb, aggXhi);
    {
        dim3 g((NN + 127) / 128, 2, NH);
        for (int rep = 0; rep < 3; rep++)
            k_gemm_l1<<<g, 256, 0, stream>>>(aggXhi, W1t, b1, x2hi);
    }

    // ---- layer 2 (att_h2 fused into gemm2 epilogue; BN=64 for 2.5 blocks/CU) ----
    {
        dim3 g((NN + 63) / 64, 4);
        k_gemm2<<<g, 256, 0, stream>>>(x2hi, W2t, asrc2, adst2, h2bf, as2, ad2);
    }

    // ---- aggregation + pool ----
    k_sm_aggr2<<<NN / 4, 256, 0, stream>>>(cnt, ssrc, as2, ad2, h2bf, b2, pooled32);

    // ---- MLP head ----
    k_mlp<<<1, 128, 0, stream>>>(pooled32, Wv1, bv1, Wv2, bv2, out);
}

// Round 22
// 195.217 us; speedup vs baseline: 1.3022x; 1.3022x over previous
//
#include <hip/hip_runtime.h>
#include <math.h>

#define NN   10000          // nodes
#define NE   160000         // raw edges
#define NET  (NE + NN)      // edges + self loops = 170000
#define FIN  70
#define HIDC 256
#define NH   4
#define D1   1024           // NH*HIDC
#define SLOPE 0.2f
#define KL1  96             // K for layer-1 GEMM (70 padded to 96)
#define NPB  32             // pooling buckets
#define BCAP 64             // per-dst edge bucket capacity (deg mean 17, P(>63)~1e-15)

typedef float f32x4 __attribute__((ext_vector_type(4)));
typedef short bf16x8 __attribute__((ext_vector_type(8)));
typedef unsigned short u16x4 __attribute__((ext_vector_type(4)));

__device__ __forceinline__ unsigned short f32_to_bf16(float f) {
    unsigned int u = __float_as_uint(f);
    unsigned int r = u + 0x7fffu + ((u >> 16) & 1u);   // round-to-nearest-even
    return (unsigned short)(r >> 16);
}
__device__ __forceinline__ float bf16_to_f32(unsigned short h) {
    return __uint_as_float(((unsigned int)h) << 16);
}
__device__ __forceinline__ float leaky(float e) { return (e > 0.f) ? e : SLOPE * e; }

// async 16B global->LDS DMA; LDS dest = wave base + lane*16 (linear), global src per-lane
__device__ __forceinline__ void cp16(const unsigned short* g, unsigned short* l) {
    __builtin_amdgcn_global_load_lds((const __attribute__((address_space(1))) unsigned int*)g,
                                     (__attribute__((address_space(3))) unsigned int*)l,
                                     16, 0, 0);
}

// ---------------- fused prep: W2t | W1t | xb | bucket scatter | att_x (self-computed was/wad) ----
// blocks: [0,64) W2t tiles ; [64,80) W1t tiles ; [80,120) xb ; [120,785) scatter ; [785,942) att_x
__global__ __launch_bounds__(256) void k_prep(const float* __restrict__ W2,
                                              unsigned short* __restrict__ W2t,
                                              const float* __restrict__ W1,
                                              unsigned short* __restrict__ W1t,
                                              const float* __restrict__ asrc,
                                              const float* __restrict__ adst,
                                              const float* __restrict__ x,
                                              unsigned short* __restrict__ xb,
                                              const int* __restrict__ ei,
                                              int* __restrict__ cnt,
                                              int* __restrict__ ssrc,
                                              float* __restrict__ asn,
                                              float* __restrict__ adn) {
    __shared__ __align__(16) char smem[20480];   // max branch: att_x 64*71*4 + 2*4*70*4 = 20416
    int b = blockIdx.x, t = threadIdx.x;
    int lane = t & 63, wave = t >> 6;
    if (b < 64) {
        // W2 [1024][256] f32 -> W2t [256][1024] bf16, LDS-tiled 64x64 transpose
        unsigned short (*tl)[68] = (unsigned short (*)[68])smem;
        int kk0 = (b >> 2) * 64, n0 = (b & 3) * 64;
        for (int i = t; i < 64 * 64; i += 256) {
            int nl = i & 63, kl = i >> 6;          // coalesced read
            tl[nl][kl] = f32_to_bf16(W2[(size_t)(kk0 + kl) * HIDC + n0 + nl]);
        }
        __syncthreads();
        for (int i = t; i < 64 * 64; i += 256) {
            int kl = i & 63, nl = i >> 6;          // coalesced write
            W2t[(size_t)(n0 + nl) * 1024 + kk0 + kl] = tl[nl][kl];
        }
    } else if (b < 80) {
        // W1 [70][1024] f32 -> W1t [1024][96] bf16 (zero-pad K), LDS-tiled 64x96
        unsigned short (*tl)[97] = (unsigned short (*)[97])smem;
        int r0 = (b - 64) * 64;
        for (int i = t; i < 64 * 96; i += 256) {
            int rl = i & 63, kk = i >> 6;
            float w = (kk < FIN) ? W1[(size_t)kk * D1 + r0 + rl] : 0.f;
            tl[rl][kk] = f32_to_bf16(w);
        }
        __syncthreads();
        for (int i = t; i < 64 * 96; i += 256) {
            int kk = i % 96, rl = i / 96;
            W1t[(size_t)(r0 + rl) * KL1 + kk] = tl[rl][kk];
        }
    } else if (b < 120) {
        // x -> bf16, vectorized float4 / u16x4 (17500 elems = 4375 vec4 per job)
        size_t base = (size_t)(b - 80) * 17500;
        for (int v = t; v < 4375; v += 256) {
            float4 xv = *(const float4*)&x[base + v * 4];
            u16x4 o;
            o[0] = f32_to_bf16(xv.x); o[1] = f32_to_bf16(xv.y);
            o[2] = f32_to_bf16(xv.z); o[3] = f32_to_bf16(xv.w);
            *(u16x4*)&xb[base + v * 4] = o;
        }
    } else if (b < 785) {
        int e = (b - 120) * 256 + t;
        if (e < NET) {
            int src, dst;
            if (e < NE) { src = ei[e]; dst = ei[NE + e]; }
            else        { src = e - NE; dst = src; }
            int pos = atomicAdd(&cnt[dst], 1);
            if (pos < BCAP) ssrc[dst * BCAP + pos] = src;
        }
    } else {
        // att_x with block-local was/wad (deterministic; reads L2-resident W1)
        int n0 = (b - 785) * 64;
        float (*xs)[71] = (float (*)[71])smem;                 // 18.2 KB
        float* lws = (float*)(smem + 64 * 71 * 4);             // [4][70]
        float* lwd = lws + NH * FIN;                           // [4][70]
        for (int i = t; i < 64 * FIN; i += 256) {
            int r = i / FIN, k = i % FIN;
            int n = n0 + r;
            xs[r][k] = (n < NN) ? x[(size_t)n * FIN + k] : 0.f;
        }
        // lane owns cols [lane*16, lane*16+16) — one head per 16-lane group
        float ar[16], dr[16];
#pragma unroll
        for (int q = 0; q < 4; q++) {
            float4 av = *(const float4*)&asrc[lane * 16 + q * 4];
            float4 dv = *(const float4*)&adst[lane * 16 + q * 4];
            ar[q*4+0]=av.x; ar[q*4+1]=av.y; ar[q*4+2]=av.z; ar[q*4+3]=av.w;
            dr[q*4+0]=dv.x; dr[q*4+1]=dv.y; dr[q*4+2]=dv.z; dr[q*4+3]=dv.w;
        }
        for (int k = wave; k < FIN; k += 4) {
            const float* row = W1 + (size_t)k * D1 + lane * 16;
            float s = 0.f, dd = 0.f;
#pragma unroll
            for (int q = 0; q < 4; q++) {
                float4 wv = *(const float4*)(row + q * 4);
                s  += wv.x*ar[q*4] + wv.y*ar[q*4+1] + wv.z*ar[q*4+2] + wv.w*ar[q*4+3];
                dd += wv.x*dr[q*4] + wv.y*dr[q*4+1] + wv.z*dr[q*4+2] + wv.w*dr[q*4+3];
            }
#pragma unroll
            for (int off = 1; off < 16; off <<= 1) { s += __shfl_xor(s, off); dd += __shfl_xor(dd, off); }
            if ((lane & 15) == 0) { int h = lane >> 4; lws[h * FIN + k] = s; lwd[h * FIN + k] = dd; }
        }
        __syncthreads();
        if (t < 64) {
            int n = n0 + t;
            if (n < NN) {
                float a[NH] = {}, d2[NH] = {};
                for (int k = 0; k < FIN; k++) {
                    float xv = xs[t][k];
#pragma unroll
                    for (int h = 0; h < NH; h++) {
                        a[h]  += xv * lws[h * FIN + k];
                        d2[h] += xv * lwd[h * FIN + k];
                    }
                }
#pragma unroll
                for (int h = 0; h < NH; h++) { asn[n*NH+h] = a[h]; adn[n*NH+h] = d2[h]; }
            }
        }
    }
}

// ---------------- fused softmax(H=4) + layer-1 aggregation (wave-per-dst, 4 dst/block) ---------
__global__ __launch_bounds__(256) void k_sm_aggX(const int* __restrict__ cnt,
                                                 const int* __restrict__ ssrc,
                                                 const float* __restrict__ as,
                                                 const float* __restrict__ ad,
                                                 const unsigned short* __restrict__ xb,
                                                 unsigned short* __restrict__ aggXhi) {
    int t = threadIdx.x, lane = t & 63, wave = t >> 6;
    int d = blockIdx.x * 4 + wave;
    int n = cnt[d]; if (n > BCAP) n = BCAP;
    float4 adv = *(const float4*)&ad[d * NH];
    bool v0 = lane < n;
    int s0 = 0;
    float e0[NH];
    if (v0) {
        s0 = ssrc[d * BCAP + lane];
        float4 a4 = *(const float4*)&as[s0 * NH];
        e0[0] = leaky(a4.x + adv.x); e0[1] = leaky(a4.y + adv.y);
        e0[2] = leaky(a4.z + adv.z); e0[3] = leaky(a4.w + adv.w);
    } else { e0[0] = e0[1] = e0[2] = e0[3] = -1e30f; }
    float m[NH] = {e0[0], e0[1], e0[2], e0[3]};
#pragma unroll
    for (int h = 0; h < NH; h++)
        for (int off = 32; off > 0; off >>= 1)
            m[h] = fmaxf(m[h], __shfl_xor(m[h], off));
    float sum[NH];
#pragma unroll
    for (int h = 0; h < NH; h++) sum[h] = v0 ? expf(e0[h] - m[h]) : 0.f;
#pragma unroll
    for (int h = 0; h < NH; h++)
        for (int off = 32; off > 0; off >>= 1)
            sum[h] += __shfl_xor(sum[h], off);
    __shared__ float al4[4][64][4];
    __shared__ int   sid[4][64];
    if (v0) {
        sid[wave][lane] = s0;
#pragma unroll
        for (int h = 0; h < NH; h++) al4[wave][lane][h] = expf(e0[h] - m[h]) / (sum[h] + 1e-16f);
    }
    __syncthreads();
    float ac[NH][2] = {};
#pragma unroll 4
    for (int j = 0; j < n; j++) {
        int s = sid[wave][j];
        float4 al = *(const float4*)al4[wave][j];
        float xv0 = bf16_to_f32(xb[(size_t)s * FIN + lane]);
        float xv1 = (lane < FIN - 64) ? bf16_to_f32(xb[(size_t)s * FIN + 64 + lane]) : 0.f;
        ac[0][0] += al.x * xv0; ac[0][1] += al.x * xv1;
        ac[1][0] += al.y * xv0; ac[1][1] += al.y * xv1;
        ac[2][0] += al.z * xv0; ac[2][1] += al.z * xv1;
        ac[3][0] += al.w * xv0; ac[3][1] += al.w * xv1;
    }
#pragma unroll
    for (int h = 0; h < NH; h++) {
        size_t base = ((size_t)d * NH + h) * KL1;
        aggXhi[base + lane] = f32_to_bf16(ac[h][0]);
        if (lane < 32) {  // k in [64,96): data for lane<6, zero pad for 6<=lane<32
            float v1 = (lane < FIN - 64) ? ac[h][1] : 0.f;
            aggXhi[base + 64 + lane] = f32_to_bf16(v1);
        }
    }
}

// ---------------- MFMA GEMM layer 1: single-stage K=96 (one barrier per block) ----------
__global__ __launch_bounds__(256) void k_gemm_l1(const unsigned short* __restrict__ aggXhi,
                                                 const unsigned short* __restrict__ W1t,
                                                 const float* __restrict__ b1,
                                                 unsigned short* __restrict__ x2hi) {
    __shared__ unsigned short As[128 * 96];   // 24 KB
    __shared__ unsigned short Bs[128 * 96];   // 24 KB
    int t = threadIdx.x;
    int n0 = blockIdx.x * 128;
    int cb = blockIdx.y * 128;       // col within head's 256
    int h  = blockIdx.z;
    int lane = t & 63, wave = t >> 6, quad = lane >> 4, l16 = lane & 15;
    int wr = (wave & 1) * 64, wc = (wave >> 1) * 64;
#pragma unroll
    for (int q = 0; q < 6; q++) {
        int g = q * 256 + t;
        int row = g / 12, gr = g % 12;
        int ra = n0 + row; if (ra >= NN) ra = NN - 1;
        cp16(aggXhi + ((size_t)ra * NH + h) * KL1 + gr * 8, As + g * 8);
        cp16(W1t + (size_t)(h * 256 + cb + row) * KL1 + gr * 8, Bs + g * 8);
    }
    __syncthreads();
    f32x4 acc[4][4] = {};
#pragma unroll
    for (int kc = 0; kc < 3; kc++) {
        bf16x8 af[4], bf[4];
#pragma unroll
        for (int i = 0; i < 4; i++) af[i] = *(const bf16x8*)&As[(wr + i * 16 + l16) * KL1 + kc * 32 + quad * 8];
#pragma unroll
        for (int j = 0; j < 4; j++) bf[j] = *(const bf16x8*)&Bs[(wc + j * 16 + l16) * KL1 + kc * 32 + quad * 8];
#pragma unroll
        for (int i = 0; i < 4; i++)
#pragma unroll
            for (int j = 0; j < 4; j++)
                acc[i][j] = __builtin_amdgcn_mfma_f32_16x16x32_bf16(af[i], bf[j], acc[i][j], 0, 0, 0);
    }
#pragma unroll
    for (int i = 0; i < 4; i++)
#pragma unroll
        for (int j = 0; j < 4; j++) {
            int colg = h * 256 + cb + wc + j * 16 + l16;
            float bb = b1[colg];
#pragma unroll
            for (int reg = 0; reg < 4; reg++) {
                int r = n0 + wr + i * 16 + quad * 4 + reg;
                if (r >= NN) continue;
                float v = fmaxf(acc[i][j][reg] + bb, 0.f);
                x2hi[(size_t)r * D1 + colg] = f32_to_bf16(v);
            }
        }
}

// ---------------- MFMA GEMM layer 2: BM=64, BN=64, 256 thr (4 waves, 2x2 of 32x32), BK=64 ------
__global__ __launch_bounds__(256) void k_gemm2(const unsigned short* __restrict__ x2hi,
                                               const unsigned short* __restrict__ W2t,
                                               const float* __restrict__ asrc,
                                               const float* __restrict__ adst,
                                               unsigned short* __restrict__ h2bf,
                                               float* __restrict__ as2,
                                               float* __restrict__ ad2) {
    __shared__ unsigned short As[64 * 64];    // 8 KB
    __shared__ unsigned short Bs[64 * 64];    // 8 KB
    int t = threadIdx.x;
    int n0 = blockIdx.x * 64;
    int cb = blockIdx.y * 64;
    int lane = t & 63, wave = t >> 6, quad = lane >> 4, l16 = lane & 15;
    int wr = (wave & 1) * 32, wc = (wave >> 1) * 32;
    const unsigned short* ga[2];
    unsigned short* la[2];
#pragma unroll
    for (int q = 0; q < 2; q++) {
        int g = q * 256 + t;
        int row = g >> 3, gr = g & 7;
        int ra = n0 + row; if (ra >= NN) ra = NN - 1;
        ga[q] = x2hi + (size_t)ra * D1 + gr * 8;
        la[q] = As + g * 8;
    }
    const unsigned short* gb[2];
    unsigned short* lb[2];
#pragma unroll
    for (int q = 0; q < 2; q++) {
        int g = q * 256 + t;
        int col = g >> 3, gr = g & 7;
        gb[q] = W2t + (size_t)(cb + col) * 1024 + gr * 8;
        lb[q] = Bs + g * 8;
    }
    f32x4 acc[2][2] = {};
    for (int kc = 0; kc < 16; kc++) {
        cp16(ga[0] + kc * 64, la[0]);
        cp16(ga[1] + kc * 64, la[1]);
        cp16(gb[0] + kc * 64, lb[0]);
        cp16(gb[1] + kc * 64, lb[1]);
        __syncthreads();
#pragma unroll
        for (int ks = 0; ks < 2; ks++) {
            bf16x8 af[2], bf[2];
#pragma unroll
            for (int i = 0; i < 2; i++) af[i] = *(const bf16x8*)&As[(wr + i * 16 + l16) * 64 + ks * 32 + quad * 8];
#pragma unroll
            for (int j = 0; j < 2; j++) bf[j] = *(const bf16x8*)&Bs[(wc + j * 16 + l16) * 64 + ks * 32 + quad * 8];
#pragma unroll
            for (int i = 0; i < 2; i++)
#pragma unroll
                for (int j = 0; j < 2; j++)
                    acc[i][j] = __builtin_amdgcn_mfma_f32_16x16x32_bf16(af[i], bf[j], acc[i][j], 0, 0, 0);
        }
        __syncthreads();
    }
    float a2[2], d2[2];
#pragma unroll
    for (int j = 0; j < 2; j++) {
        int c = cb + wc + j * 16 + l16;
        a2[j] = asrc[c];
        d2[j] = adst[c];
    }
    float asp[2][4] = {}, adp[2][4] = {};
#pragma unroll
    for (int i = 0; i < 2; i++)
#pragma unroll
        for (int j = 0; j < 2; j++) {
            int c = cb + wc + j * 16 + l16;
#pragma unroll
            for (int reg = 0; reg < 4; reg++) {
                int r = n0 + wr + i * 16 + quad * 4 + reg;
                float v = acc[i][j][reg];
                if (r < NN) h2bf[(size_t)r * HIDC + c] = f32_to_bf16(v);
                asp[i][reg] += v * a2[j];
                adp[i][reg] += v * d2[j];
            }
        }
#pragma unroll
    for (int mask = 1; mask < 16; mask <<= 1)
#pragma unroll
        for (int i = 0; i < 2; i++)
#pragma unroll
            for (int reg = 0; reg < 4; reg++) {
                asp[i][reg] += __shfl_xor(asp[i][reg], mask);
                adp[i][reg] += __shfl_xor(adp[i][reg], mask);
            }
    if (l16 == 0) {
#pragma unroll
        for (int i = 0; i < 2; i++)
#pragma unroll
            for (int reg = 0; reg < 4; reg++) {
                int r = n0 + wr + i * 16 + quad * 4 + reg;
                if (r < NN) {
                    atomicAdd(&as2[r], asp[i][reg]);
                    atomicAdd(&ad2[r], adp[i][reg]);
                }
            }
    }
}

// ---------------- fused softmax(H=1) + layer-2 aggregation + bucketed pool ------------
// wave-per-dst: 4 dsts/block; no fence, no finale (round-8 PMC: per-block __threadfence()
// = L2 writeback on gfx950, 194 us of stall).
__global__ __launch_bounds__(256) void k_sm_aggr2(const int* __restrict__ cnt,
                                                  const int* __restrict__ ssrc,
                                                  const float* __restrict__ as,
                                                  const float* __restrict__ ad,
                                                  const unsigned short* __restrict__ h2bf,
                                                  const float* __restrict__ b,
                                                  float* __restrict__ pooled32) {
    int t = threadIdx.x, lane = t & 63, wave = t >> 6;
    int d = blockIdx.x * 4 + wave;
    int n = cnt[d]; if (n > BCAP) n = BCAP;
    float adv = ad[d];
    bool v0 = lane < n;
    int s0 = v0 ? ssrc[d * BCAP + lane] : 0;
    float e0 = v0 ? leaky(as[s0] + adv) : -1e30f;
    float m = e0;
    for (int off = 32; off > 0; off >>= 1) m = fmaxf(m, __shfl_xor(m, off));
    float ex = v0 ? expf(e0 - m) : 0.f;
    float sum = ex;
    for (int off = 32; off > 0; off >>= 1) sum += __shfl_xor(sum, off);
    float al0 = ex * (1.0f / (sum + 1e-16f));
    float a0 = 0.f, a1 = 0.f, a2v = 0.f, a3 = 0.f;
#pragma unroll 4
    for (int j = 0; j < n; j++) {
        float alj = __shfl(al0, j);          // wave-uniform j -> v_readlane broadcast
        int   sj  = __shfl(s0, j);
        u16x4 hv = *(const u16x4*)&h2bf[(size_t)sj * HIDC + lane * 4];
        a0  += alj * bf16_to_f32(hv[0]);
        a1  += alj * bf16_to_f32(hv[1]);
        a2v += alj * bf16_to_f32(hv[2]);
        a3  += alj * bf16_to_f32(hv[3]);
    }
    float4 bb = *(const float4*)&b[lane * 4];
    __shared__ float sacc[4 * 256];
    *(float4*)&sacc[wave * 256 + lane * 4] = make_float4(fmaxf(a0 + bb.x, 0.f),
                                                         fmaxf(a1 + bb.y, 0.f),
                                                         fmaxf(a2v + bb.z, 0.f),
                                                         fmaxf(a3 + bb.w, 0.f));
    __syncthreads();
    float s = sacc[t] + sacc[256 + t] + sacc[512 + t] + sacc[768 + t];
    atomicAdd(&pooled32[(blockIdx.x & (NPB - 1)) * HIDC + t], s);
}

// ---------------- MLP head: bucket-reduce + 256 -> 128 (gelu exact) -> 1 ----------------
__global__ __launch_bounds__(128) void k_mlp(const float* __restrict__ pooled32,
                                             const float* __restrict__ Wv1,
                                             const float* __restrict__ bv1,
                                             const float* __restrict__ Wv2,
                                             const float* __restrict__ bv2,
                                             float* __restrict__ out) {
    int j = threadIdx.x;
    __shared__ float ps[256];
    for (int c = j; c < HIDC; c += 128) {
        float s = 0.f;
        for (int bkt = 0; bkt < NPB; bkt++) s += pooled32[bkt * HIDC + c];
        ps[c] = s;
    }
    __syncthreads();
    float s = bv1[j];
    const float invn = 1.0f / (float)NN;
    for (int c = 0; c < HIDC; c++)
        s += (ps[c] * invn) * Wv1[c * 128 + j];
    float g = 0.5f * s * (1.0f + erff(s * 0.70710678118654752f));
    float v = g * Wv2[j];
    __shared__ float red[128];
    red[j] = v;
    __syncthreads();
    for (int off = 64; off > 0; off >>= 1) {
        if (j < off) red[j] += red[j + off];
        __syncthreads();
    }
    if (j == 0) out[0] = red[0] + bv2[0];
}

extern "C" void kernel_launch(void* const* d_in, const int* in_sizes, int n_in,
                              void* d_out, int out_size, void* d_ws, size_t ws_size,
                              hipStream_t stream) {
    const float* x_in  = (const float*)d_in[0];
    const int*   ei    = (const int*)d_in[1];
    // d_in[2] = edge_attr: ignored (GATConv has no edge_dim)
    const float* W1    = (const float*)d_in[3];
    const float* asrc1 = (const float*)d_in[4];
    const float* adst1 = (const float*)d_in[5];
    const float* b1    = (const float*)d_in[6];
    const float* W2    = (const float*)d_in[7];
    const float* asrc2 = (const float*)d_in[8];
    const float* adst2 = (const float*)d_in[9];
    const float* b2    = (const float*)d_in[10];
    const float* Wv1   = (const float*)d_in[11];
    const float* bv1   = (const float*)d_in[12];
    const float* Wv2   = (const float*)d_in[13];
    const float* bv2   = (const float*)d_in[14];
    float* out = (float*)d_out;

    char* w = (char*)d_ws;
    auto alloc = [&](size_t bytes) { char* p = w; w += (bytes + 255) & ~(size_t)255; return p; };
    unsigned short* x2hi   = (unsigned short*)alloc(2ull * NN * D1);           // 20.5 MB
    unsigned short* aggXhi = (unsigned short*)alloc(2ull * NN * NH * KL1);     // 7.68 MB
    unsigned short* h2bf = (unsigned short*)alloc(2ull * NN * HIDC);           // 5.12 MB
    unsigned short* xb   = (unsigned short*)alloc(2ull * NN * FIN);            // 1.4 MB
    unsigned short* W2t  = (unsigned short*)alloc(2ull * 256 * 1024);          // 0.52 MB
    unsigned short* W1t  = (unsigned short*)alloc(2ull * NH * 256 * KL1);      // 0.20 MB
    float* as1    = (float*)alloc(sizeof(float) * NN * NH);
    float* ad1    = (float*)alloc(sizeof(float) * NN * NH);
    int*   ssrc   = (int*)alloc(sizeof(int) * NN * BCAP);                      // 2.56 MB
    // single zero-init region: cnt | pooled32 | as2 | ad2 (one memset)
    size_t zbytes = (size_t)NN * 4 + NPB * HIDC * 4 + NN * 4 + NN * 4;
    char*  zbase  = alloc(zbytes);
    int*   cnt      = (int*)zbase;
    float* pooled32 = (float*)(zbase + NN * 4);
    float* as2      = (float*)(zbase + NN * 4 + NPB * HIDC * 4);
    float* ad2      = (float*)(zbase + NN * 4 + NPB * HIDC * 4 + NN * 4);

    hipMemsetAsync(zbase, 0, zbytes, stream);

    // prep: weight conversions + xb + bucket scatter + att_x (self-computed was/wad)
    k_prep<<<64 + 16 + 40 + 665 + 157, 256, 0, stream>>>(
        W2, W2t, W1, W1t, asrc1, adst1, x_in, xb, ei, cnt, ssrc, as1, ad1);

    // ---- layer 1 ----
    k_sm_aggX<<<NN / 4, 256, 0, stream>>>(cnt, ssrc, as1, ad1, xb, aggXhi);
    {
        dim3 g((NN + 127) / 128, 2, NH);
        k_gemm_l1<<<g, 256, 0, stream>>>(aggXhi, W1t, b1, x2hi);
    }

    // ---- layer 2 (att_h2 fused into gemm2 epilogue; BN=64 for 2.5 blocks/CU) ----
    {
        dim3 g((NN + 63) / 64, 4);
        k_gemm2<<<g, 256, 0, stream>>>(x2hi, W2t, asrc2, adst2, h2bf, as2, ad2);
    }

    // ---- aggregation + pool ----
    k_sm_aggr2<<<NN / 4, 256, 0, stream>>>(cnt, ssrc, as2, ad2, h2bf, b2, pooled32);

    // ---- MLP head ----
    k_mlp<<<1, 128, 0, stream>>>(pooled32, Wv1, bv1, Wv2, bv2, out);
}